// Round 6
// baseline (75.081 us; speedup 1.0000x reference)
//
#include <hip/hip_runtime.h>

#define NBATCH 4096
#define NSAMP  7
#define DIM    512

typedef float floatx4 __attribute__((ext_vector_type(4)));
typedef short short8  __attribute__((ext_vector_type(8)));

__device__ static __forceinline__ void load16_lds(const void* g, void* l) {
  __builtin_amdgcn_global_load_lds(
      (const __attribute__((address_space(1))) unsigned int*)g,
      (__attribute__((address_space(3))) unsigned int*)l, 16, 0, 0);
}

__device__ static __forceinline__ unsigned int f2bf_rne(float f) {
  union { float f; unsigned int u; } v; v.f = f;
  unsigned int u = v.u;
  u += 0x7FFFu + ((u >> 16) & 1u);
  return u >> 16;
}

// ---------------- preprocess: out[i,d] = mean_norm[i,d] + esum[i,d]*exp(ls[i,d])/7 ----
// One WAVE per row (8192 rows = 2 sides x 4096). 2048 blocks x 256 threads.
// The asm keep-alive consumes ALL 18 loaded float4s at once: regalloc must keep
// 72 data VGPRs live -> cannot strip-mine the loads (R3-R5: VGPR=36, ~4 loads
// in flight, 50us latency-bound). launch_bounds(256,3): VGPR cap ~170.
__global__ __launch_bounds__(256, 3) void prep_kernel(
    const float* __restrict__ qm, const float* __restrict__ qls, const float* __restrict__ eq,
    const float* __restrict__ tm, const float* __restrict__ tls, const float* __restrict__ ek,
    unsigned short* __restrict__ outA, unsigned short* __restrict__ outB)
{
  const int wv   = threadIdx.x >> 6;
  const int lane = threadIdx.x & 63;
  const int gid  = blockIdx.x * 4 + wv;   // 0..8191
  const int side = gid >> 12;             // 0: query, 1: target
  const int row  = gid & (NBATCH - 1);

  const float* mean = side ? tm  : qm;
  const float* ls   = side ? tls : qls;
  const float* eps  = side ? ek  : eq;
  unsigned short* out = side ? outB : outA;

  const floatx4* mean4 = (const floatx4*)(mean + (size_t)row * DIM);
  const floatx4* ls4   = (const floatx4*)(ls   + (size_t)row * DIM);
  const floatx4* eps4  = (const floatx4*)(eps  + (size_t)row * (NSAMP * DIM));

  // ---- issue ALL loads; keep-alive asm forces simultaneous liveness ----
  const floatx4 m0 = mean4[lane];
  const floatx4 m1 = mean4[64 + lane];
  const floatx4 l0 = ls4[lane];
  const floatx4 l1 = ls4[64 + lane];
  const floatx4 e00 = eps4[0 * (DIM / 4) + lane];
  const floatx4 e01 = eps4[1 * (DIM / 4) + lane];
  const floatx4 e02 = eps4[2 * (DIM / 4) + lane];
  const floatx4 e03 = eps4[3 * (DIM / 4) + lane];
  const floatx4 e04 = eps4[4 * (DIM / 4) + lane];
  const floatx4 e05 = eps4[5 * (DIM / 4) + lane];
  const floatx4 e06 = eps4[6 * (DIM / 4) + lane];
  const floatx4 e10 = eps4[0 * (DIM / 4) + 64 + lane];
  const floatx4 e11 = eps4[1 * (DIM / 4) + 64 + lane];
  const floatx4 e12 = eps4[2 * (DIM / 4) + 64 + lane];
  const floatx4 e13 = eps4[3 * (DIM / 4) + 64 + lane];
  const floatx4 e14 = eps4[4 * (DIM / 4) + 64 + lane];
  const floatx4 e15 = eps4[5 * (DIM / 4) + 64 + lane];
  const floatx4 e16 = eps4[6 * (DIM / 4) + 64 + lane];
  asm volatile("" ::
      "v"(m0), "v"(m1), "v"(l0), "v"(l1),
      "v"(e00), "v"(e01), "v"(e02), "v"(e03), "v"(e04), "v"(e05), "v"(e06),
      "v"(e10), "v"(e11), "v"(e12), "v"(e13), "v"(e14), "v"(e15), "v"(e16));
  __builtin_amdgcn_sched_barrier(0);

  float ss = m0[0] * m0[0] + m0[1] * m0[1] + m0[2] * m0[2] + m0[3] * m0[3]
           + m1[0] * m1[0] + m1[1] * m1[1] + m1[2] * m1[2] + m1[3] * m1[3];
  #pragma unroll
  for (int off = 1; off < 64; off <<= 1) ss += __shfl_xor(ss, off);
  const float rnorm = 1.0f / fmaxf(sqrtf(ss), 1e-12f);

  const float s00 = e00[0] + e01[0] + e02[0] + e03[0] + e04[0] + e05[0] + e06[0];
  const float s01 = e00[1] + e01[1] + e02[1] + e03[1] + e04[1] + e05[1] + e06[1];
  const float s02 = e00[2] + e01[2] + e02[2] + e03[2] + e04[2] + e05[2] + e06[2];
  const float s03 = e00[3] + e01[3] + e02[3] + e03[3] + e04[3] + e05[3] + e06[3];
  const float s10 = e10[0] + e11[0] + e12[0] + e13[0] + e14[0] + e15[0] + e16[0];
  const float s11 = e10[1] + e11[1] + e12[1] + e13[1] + e14[1] + e15[1] + e16[1];
  const float s12 = e10[2] + e11[2] + e12[2] + e13[2] + e14[2] + e15[2] + e16[2];
  const float s13 = e10[3] + e11[3] + e12[3] + e13[3] + e14[3] + e15[3] + e16[3];

  const float inv = 1.0f / (float)NSAMP;
  const float v00 = m0[0] * rnorm + s00 * (__expf(l0[0]) * inv);
  const float v01 = m0[1] * rnorm + s01 * (__expf(l0[1]) * inv);
  const float v02 = m0[2] * rnorm + s02 * (__expf(l0[2]) * inv);
  const float v03 = m0[3] * rnorm + s03 * (__expf(l0[3]) * inv);
  const float v10 = m1[0] * rnorm + s10 * (__expf(l1[0]) * inv);
  const float v11 = m1[1] * rnorm + s11 * (__expf(l1[1]) * inv);
  const float v12 = m1[2] * rnorm + s12 * (__expf(l1[2]) * inv);
  const float v13 = m1[3] * rnorm + s13 * (__expf(l1[3]) * inv);

  unsigned int* o32 = (unsigned int*)(out + (size_t)row * DIM);
  uint2 p0, p1;
  p0.x = f2bf_rne(v00) | (f2bf_rne(v01) << 16);
  p0.y = f2bf_rne(v02) | (f2bf_rne(v03) << 16);
  p1.x = f2bf_rne(v10) | (f2bf_rne(v11) << 16);
  p1.y = f2bf_rne(v12) | (f2bf_rne(v13) << 16);
  ((uint2*)o32)[lane] = p0;
  ((uint2*)(o32 + 128))[lane] = p1;
}

// ---------------- fused GEMM + per-block LSE partials ----------------
// S = A * B^T (both [4096,512] bf16, K-contiguous). 128x128 tile, 4 waves (2x2),
// each wave 64x64 via 4x4 frags of mfma_f32_16x16x32_bf16. BK=32, single LDS buf.
// Per-row partial (max, sum) over this block's 128 columns -> partial[row][tileCol].
#define BM 128
#define BN 128
#define BK 32
#define NCB (NBATCH / BN)   // 32 column blocks

__global__ __launch_bounds__(256) void gemm_lse_kernel(
    const unsigned short* __restrict__ Abf, const unsigned short* __restrict__ Bbf,
    float2* __restrict__ partial, float* __restrict__ diag)
{
  __shared__ unsigned short sA[BM * BK];  // 8 KB
  __shared__ unsigned short sB[BN * BK];  // 8 KB
  __shared__ float2 part[BM][2];          // per-row (max,sum) per wave-column

  const int tid  = threadIdx.x;
  const int lane = tid & 63;
  const int wv   = tid >> 6;   // 0..3
  const int wr   = wv >> 1;    // wave row 0..1
  const int wc   = wv & 1;     // wave col 0..1

  const int tileRow = blockIdx.y;
  const int tileCol = blockIdx.x;

  floatx4 acc[4][4];
  #pragma unroll
  for (int m = 0; m < 4; ++m)
    #pragma unroll
    for (int n = 0; n < 4; ++n)
      acc[m][n] = (floatx4){0.f, 0.f, 0.f, 0.f};

  const int srow   = wv * 32 + (lane >> 2);
  const int spiece = (lane & 3) * 16;  // 16B piece within the 64 B row

  const char* gA0 = (const char*)Abf + (size_t)(tileRow * BM + srow) * (DIM * 2) + spiece;
  const char* gA1 = gA0 + 16 * (DIM * 2);
  const char* gB0 = (const char*)Bbf + (size_t)(tileCol * BN + srow) * (DIM * 2) + spiece;
  const char* gB1 = gB0 + 16 * (DIM * 2);
  char* lA0 = (char*)sA + wv * 2048;
  char* lA1 = lA0 + 1024;
  char* lB0 = (char*)sB + wv * 2048;
  char* lB1 = lB0 + 1024;

  const int fr = lane & 15;   // fragment row/col index (0..15)
  const int kg = lane >> 4;   // k-chunk of 8 (0..3)

  for (int kt = 0; kt < DIM / BK; ++kt) {
    const size_t ko = (size_t)kt * (BK * 2);  // 64 B per K-step
    load16_lds(gA0 + ko, lA0);
    load16_lds(gA1 + ko, lA1);
    load16_lds(gB0 + ko, lB0);
    load16_lds(gB1 + ko, lB1);
    __syncthreads();  // drains vmcnt -> LDS tiles ready

    short8 af[4], bfr[4];
    #pragma unroll
    for (int m = 0; m < 4; ++m)
      af[m] = *(const short8*)&sA[(wr * 64 + m * 16 + fr) * BK + kg * 8];
    #pragma unroll
    for (int n = 0; n < 4; ++n)
      bfr[n] = *(const short8*)&sB[(wc * 64 + n * 16 + fr) * BK + kg * 8];

    #pragma unroll
    for (int m = 0; m < 4; ++m)
      #pragma unroll
      for (int n = 0; n < 4; ++n)
        acc[m][n] = __builtin_amdgcn_mfma_f32_16x16x32_bf16(af[m], bfr[n], acc[m][n], 0, 0, 0);

    __syncthreads();  // all waves done reading LDS before next stage
  }

  // epilogue: per-row (max, sum-of-exp) over this wave's 64 columns, then
  // merge the two wave-columns in LDS, write partial[row][tileCol].
  const int rowBase = tileRow * BM + wr * 64;
  const int colBase = tileCol * BN + wc * 64;
  #pragma unroll
  for (int m = 0; m < 4; ++m) {
    #pragma unroll
    for (int r = 0; r < 4; ++r) {
      const int gi = rowBase + m * 16 + kg * 4 + r;
      float lm = -3.0e38f;
      #pragma unroll
      for (int n = 0; n < 4; ++n) {
        const float c = acc[m][n][r];
        const int gj = colBase + n * 16 + fr;
        if (gi == gj) diag[gi] = c;   // exact f32 S[i,i]
        lm = fmaxf(lm, c);
      }
      #pragma unroll
      for (int off = 1; off < 16; off <<= 1) lm = fmaxf(lm, __shfl_xor(lm, off));
      float s = 0.f;
      #pragma unroll
      for (int n = 0; n < 4; ++n) s += __expf(acc[m][n][r] - lm);
      #pragma unroll
      for (int off = 1; off < 16; off <<= 1) s += __shfl_xor(s, off);
      if (fr == 0) part[wr * 64 + m * 16 + kg * 4 + r][wc] = make_float2(lm, s);
    }
  }
  __syncthreads();
  if (tid < BM) {
    const float2 p0 = part[tid][0];
    const float2 p1 = part[tid][1];
    const float M = fmaxf(p0.x, p1.x);
    const float S = p0.y * __expf(p0.x - M) + p1.y * __expf(p1.x - M);
    partial[(size_t)(tileRow * BM + tid) * NCB + tileCol] = make_float2(M, S);
  }
}

// ---------------- finalize 1: per-row LSE merge + per-block loss partial ----
__global__ __launch_bounds__(256) void finalize1_kernel(
    const float2* __restrict__ partial, const float* __restrict__ diag,
    float* __restrict__ blocksum)
{
  const int i = blockIdx.x * 256 + threadIdx.x;  // row
  const float2* p = partial + (size_t)i * NCB;
  float M = -3.0e38f;
  #pragma unroll 8
  for (int k = 0; k < NCB; ++k) M = fmaxf(M, p[k].x);
  float S = 0.f;
  #pragma unroll 8
  for (int k = 0; k < NCB; ++k) S += p[k].y * __expf(p[k].x - M);
  float v = M + logf(S) - diag[i];

  #pragma unroll
  for (int off = 1; off < 64; off <<= 1) v += __shfl_xor(v, off);
  __shared__ float wss[4];
  if ((threadIdx.x & 63) == 0) wss[threadIdx.x >> 6] = v;
  __syncthreads();
  if (threadIdx.x == 0)
    blocksum[blockIdx.x] = wss[0] + wss[1] + wss[2] + wss[3];
}

// ---------------- finalize 2: sum 16 block partials, divide ----------------
__global__ void finalize2_kernel(const float* __restrict__ blocksum, float* __restrict__ out)
{
  float s = 0.f;
  #pragma unroll
  for (int k = 0; k < 16; ++k) s += blocksum[k];
  out[0] = s * (1.0f / (float)NBATCH);
}

extern "C" void kernel_launch(void* const* d_in, const int* in_sizes, int n_in,
                              void* d_out, int out_size, void* d_ws, size_t ws_size,
                              hipStream_t stream) {
  const float* qm  = (const float*)d_in[0];
  const float* qls = (const float*)d_in[1];
  const float* tm  = (const float*)d_in[2];
  const float* tls = (const float*)d_in[3];
  const float* eq  = (const float*)d_in[4];
  const float* ek  = (const float*)d_in[5];
  float* out = (float*)d_out;

  char* ws = (char*)d_ws;
  unsigned short* Abf = (unsigned short*)ws;                        // 4 MB
  unsigned short* Bbf = (unsigned short*)(ws + (size_t)4194304);    // 4 MB
  float2* partial = (float2*)(ws + (size_t)8388608);                // 1 MB
  float*  diag    = (float*)(ws + (size_t)8388608 + 1048576);       // 16 KB
  float*  blocksum= (float*)(ws + (size_t)8388608 + 1048576 + 16384); // 64 B

  prep_kernel<<<dim3(NBATCH * 2 / 4), 256, 0, stream>>>(qm, qls, eq, tm, tls, ek, Abf, Bbf);
  gemm_lse_kernel<<<dim3(NBATCH / BN, NBATCH / BM), 256, 0, stream>>>(Abf, Bbf, partial, diag);
  finalize1_kernel<<<NBATCH / 256, 256, 0, stream>>>(partial, diag, blocksum);
  finalize2_kernel<<<1, 1, 0, stream>>>(blocksum, out);
}

// Round 7
// 59.720 us; speedup vs baseline: 1.2572x; 1.2572x over previous
//
#include <hip/hip_runtime.h>

#define NBATCH 4096
#define NSAMP  7
#define DIM    512
#define NCB    16   // 4096 / 256 column tiles

typedef float floatx4 __attribute__((ext_vector_type(4)));
typedef short short8  __attribute__((ext_vector_type(8)));

__device__ static __forceinline__ void load16_lds(const void* g, void* l) {
  __builtin_amdgcn_global_load_lds(
      (const __attribute__((address_space(1))) unsigned int*)g,
      (__attribute__((address_space(3))) unsigned int*)l, 16, 0, 0);
}

__device__ static __forceinline__ unsigned int f2bf_rne(float f) {
  union { float f; unsigned int u; } v; v.f = f;
  unsigned int u = v.u;
  u += 0x7FFFu + ((u >> 16) & 1u);
  return u >> 16;
}

// ---------------- preprocess: out[i,d] = mean_norm[i,d] + esum[i,d]*exp(ls[i,d])/7 ----
// One WAVE per row. At its roofline: 151 MB read at ~3.1 TB/s read-path cap ~= 48us
// (R3-R6: three codegen structures all pinned here; warm L3 replays identical).
__global__ __launch_bounds__(256, 4) void prep_kernel(
    const float* __restrict__ qm, const float* __restrict__ qls, const float* __restrict__ eq,
    const float* __restrict__ tm, const float* __restrict__ tls, const float* __restrict__ ek,
    unsigned short* __restrict__ outA, unsigned short* __restrict__ outB)
{
  const int wv   = threadIdx.x >> 6;
  const int lane = threadIdx.x & 63;
  const int gid  = blockIdx.x * 4 + wv;   // 0..8191
  const int side = gid >> 12;             // 0: query, 1: target
  const int row  = gid & (NBATCH - 1);

  const float* mean = side ? tm  : qm;
  const float* ls   = side ? tls : qls;
  const float* eps  = side ? ek  : eq;
  unsigned short* out = side ? outB : outA;

  const float4* mean4 = (const float4*)(mean + (size_t)row * DIM);
  const float4* ls4   = (const float4*)(ls   + (size_t)row * DIM);
  const float4* eps4  = (const float4*)(eps  + (size_t)row * (NSAMP * DIM));

  const float4 m0 = mean4[lane];
  const float4 m1 = mean4[64 + lane];
  const float4 l0 = ls4[lane];
  const float4 l1 = ls4[64 + lane];
  float4 e0[NSAMP], e1[NSAMP];
  #pragma unroll
  for (int n = 0; n < NSAMP; ++n) {
    e0[n] = eps4[n * (DIM / 4) + lane];
    e1[n] = eps4[n * (DIM / 4) + 64 + lane];
  }

  float ss = m0.x * m0.x + m0.y * m0.y + m0.z * m0.z + m0.w * m0.w
           + m1.x * m1.x + m1.y * m1.y + m1.z * m1.z + m1.w * m1.w;
  #pragma unroll
  for (int off = 1; off < 64; off <<= 1) ss += __shfl_xor(ss, off);
  const float rnorm = 1.0f / fmaxf(sqrtf(ss), 1e-12f);

  float s00 = 0.f, s01 = 0.f, s02 = 0.f, s03 = 0.f;
  float s10 = 0.f, s11 = 0.f, s12 = 0.f, s13 = 0.f;
  #pragma unroll
  for (int n = 0; n < NSAMP; ++n) {
    s00 += e0[n].x; s01 += e0[n].y; s02 += e0[n].z; s03 += e0[n].w;
    s10 += e1[n].x; s11 += e1[n].y; s12 += e1[n].z; s13 += e1[n].w;
  }

  const float inv = 1.0f / (float)NSAMP;
  const float v00 = m0.x * rnorm + s00 * (__expf(l0.x) * inv);
  const float v01 = m0.y * rnorm + s01 * (__expf(l0.y) * inv);
  const float v02 = m0.z * rnorm + s02 * (__expf(l0.z) * inv);
  const float v03 = m0.w * rnorm + s03 * (__expf(l0.w) * inv);
  const float v10 = m1.x * rnorm + s10 * (__expf(l1.x) * inv);
  const float v11 = m1.y * rnorm + s11 * (__expf(l1.y) * inv);
  const float v12 = m1.z * rnorm + s12 * (__expf(l1.z) * inv);
  const float v13 = m1.w * rnorm + s13 * (__expf(l1.w) * inv);

  unsigned int* o32 = (unsigned int*)(out + (size_t)row * DIM);
  uint2 p0, p1;
  p0.x = f2bf_rne(v00) | (f2bf_rne(v01) << 16);
  p0.y = f2bf_rne(v02) | (f2bf_rne(v03) << 16);
  p1.x = f2bf_rne(v10) | (f2bf_rne(v11) << 16);
  p1.y = f2bf_rne(v12) | (f2bf_rne(v13) << 16);
  ((uint2*)o32)[lane] = p0;
  ((uint2*)(o32 + 128))[lane] = p1;
}

// ---------------- fused 256x256 GEMM + per-block LSE partials ----------------
// S = A*B^T, A,B [4096,512] bf16 K-contiguous. 256^2 tile, 8 waves (2Mx4N),
// BK=64, double-buffered LDS (128 KB), phase-split K-loop, XOR-swizzled LDS
// (byte ^= (row&7)<<4; pre-swizzled global source so gload_lds's linear write
// lands swizzled -- rule #21 both-sides). Per-wave C: 128x64 = acc[8][4].
// LDS layout per buffer (65536 B): A tile 256x64bf16 at +0, B tile at +32768;
// row stride 128 B; 16-B chunk c16 stored at (c16 ^ (row&7)).

__device__ static __forceinline__ void stage_half(
    const unsigned short* __restrict__ Abf, const unsigned short* __restrict__ Bbf,
    int tileRow, int tileCol, int h, int kt, char* ldsbuf, int tid)
{
  const char* gsrc;
  if (h < 2) gsrc = (const char*)Abf + ((size_t)(tileRow * 256 + h * 128)) * (DIM * 2) + (size_t)kt * 128;
  else       gsrc = (const char*)Bbf + ((size_t)(tileCol * 256 + (h - 2) * 128)) * (DIM * 2) + (size_t)kt * 128;
  char* ldst = ldsbuf + h * 16384;
  #pragma unroll
  for (int q = 0; q < 2; ++q) {
    const int slot = q * 512 + tid;
    const int r    = slot >> 3;
    const int sc   = (slot & 7) ^ (r & 7);           // inverse-swizzled source chunk
    load16_lds(gsrc + (size_t)r * (DIM * 2) + sc * 16, ldst + slot * 16);
  }
}

__device__ static __forceinline__ short8 lds_frag(const char* base, int R, int c16) {
  return *(const short8*)(base + R * 128 + (((c16 ^ (R & 7)) << 4)));
}

__global__ __launch_bounds__(512) void gemm_lse_kernel(
    const unsigned short* __restrict__ Abf, const unsigned short* __restrict__ Bbf,
    float2* __restrict__ partial, float* __restrict__ diag)
{
  extern __shared__ char lds[];   // 131072 B, passed at launch

  const int tid  = threadIdx.x;
  const int lane = tid & 63;
  const int wv   = tid >> 6;     // 0..7
  const int wm   = wv >> 2;      // 0..1  (M half)
  const int wn   = wv & 3;       // 0..3  (N quarter)
  const int fr   = lane & 15;
  const int kg   = lane >> 4;

  const int tileRow = blockIdx.y;
  const int tileCol = blockIdx.x;

  floatx4 acc[8][4];
  #pragma unroll
  for (int m = 0; m < 8; ++m)
    #pragma unroll
    for (int n = 0; n < 4; ++n)
      acc[m][n] = (floatx4){0.f, 0.f, 0.f, 0.f};

  // prologue: stage K-tile 0 into buffer 0
  #pragma unroll
  for (int h = 0; h < 4; ++h)
    stage_half(Abf, Bbf, tileRow, tileCol, h, 0, lds, tid);
  __syncthreads();   // vmcnt(0) drain -> tile 0 ready

  short8 bb[4][2];
  for (int t = 0; t < 8; ++t) {
    const int ct = t & 1;
    const char* bA = lds + ct * 65536;
    const char* bB = bA + 32768;
    char* nbuf = lds + (ct ^ 1) * 65536;

    #pragma unroll
    for (int p = 0; p < 4; ++p) {
      // stage one half-tile of K-tile t+1 (stays in flight across phases)
      if (t < 7) stage_half(Abf, Bbf, tileRow, tileCol, p, t + 1, nbuf, tid);

      // A fragments for this phase's two M-rows (both 32-K steps)
      const short8 a00 = lds_frag(bA, wm * 128 + (2 * p + 0) * 16 + fr, kg);
      const short8 a01 = lds_frag(bA, wm * 128 + (2 * p + 0) * 16 + fr, 4 + kg);
      const short8 a10 = lds_frag(bA, wm * 128 + (2 * p + 1) * 16 + fr, kg);
      const short8 a11 = lds_frag(bA, wm * 128 + (2 * p + 1) * 16 + fr, 4 + kg);
      if (p == 0) {
        #pragma unroll
        for (int n = 0; n < 4; ++n) {
          bb[n][0] = lds_frag(bB, wn * 64 + n * 16 + fr, kg);
          bb[n][1] = lds_frag(bB, wn * 64 + n * 16 + fr, 4 + kg);
        }
      }

      __builtin_amdgcn_s_barrier();
      __builtin_amdgcn_s_setprio(1);
      #pragma unroll
      for (int n = 0; n < 4; ++n) {
        acc[2 * p + 0][n] = __builtin_amdgcn_mfma_f32_16x16x32_bf16(a00, bb[n][0], acc[2 * p + 0][n], 0, 0, 0);
        acc[2 * p + 0][n] = __builtin_amdgcn_mfma_f32_16x16x32_bf16(a01, bb[n][1], acc[2 * p + 0][n], 0, 0, 0);
        acc[2 * p + 1][n] = __builtin_amdgcn_mfma_f32_16x16x32_bf16(a10, bb[n][0], acc[2 * p + 1][n], 0, 0, 0);
        acc[2 * p + 1][n] = __builtin_amdgcn_mfma_f32_16x16x32_bf16(a11, bb[n][1], acc[2 * p + 1][n], 0, 0, 0);
      }
      __builtin_amdgcn_s_setprio(0);
      __builtin_amdgcn_s_barrier();
    }
    __syncthreads();  // drain: next tile's staged halves landed (L2-resident, issued phases ago)
  }

  // epilogue: per-row (max,sum) over this wave's 64 cols -> LDS merge over 4 wn.
  float2* part = (float2*)lds;   // 256 rows x 4 wn (K-loop done, buffers dead)
  #pragma unroll
  for (int m = 0; m < 8; ++m) {
    #pragma unroll
    for (int rr = 0; rr < 4; ++rr) {
      const int lrow = wm * 128 + m * 16 + kg * 4 + rr;
      const int gi = tileRow * 256 + lrow;
      float lm = -3.0e38f;
      #pragma unroll
      for (int n = 0; n < 4; ++n) {
        const float c = acc[m][n][rr];
        const int gj = tileCol * 256 + wn * 64 + n * 16 + fr;
        if (gi == gj) diag[gi] = c;   // exact f32 S[i,i]
        lm = fmaxf(lm, c);
      }
      #pragma unroll
      for (int off = 1; off < 16; off <<= 1) lm = fmaxf(lm, __shfl_xor(lm, off));
      float s = 0.f;
      #pragma unroll
      for (int n = 0; n < 4; ++n) s += __expf(acc[m][n][rr] - lm);
      #pragma unroll
      for (int off = 1; off < 16; off <<= 1) s += __shfl_xor(s, off);
      if (fr == 0) part[lrow * 4 + wn] = make_float2(lm, s);
    }
  }
  __syncthreads();
  if (tid < 256) {
    float2 p0 = part[tid * 4 + 0], p1 = part[tid * 4 + 1];
    float2 p2 = part[tid * 4 + 2], p3 = part[tid * 4 + 3];
    float M = fmaxf(fmaxf(p0.x, p1.x), fmaxf(p2.x, p3.x));
    float S = p0.y * __expf(p0.x - M) + p1.y * __expf(p1.x - M)
            + p2.y * __expf(p2.x - M) + p3.y * __expf(p3.x - M);
    partial[(size_t)(tileRow * 256 + tid) * NCB + tileCol] = make_float2(M, S);
  }
}

// ---------------- finalize 1: per-row LSE merge + per-block loss partial ----
__global__ __launch_bounds__(256) void finalize1_kernel(
    const float2* __restrict__ partial, const float* __restrict__ diag,
    float* __restrict__ blocksum)
{
  const int i = blockIdx.x * 256 + threadIdx.x;  // row
  const float2* p = partial + (size_t)i * NCB;
  float M = -3.0e38f;
  #pragma unroll
  for (int k = 0; k < NCB; ++k) M = fmaxf(M, p[k].x);
  float S = 0.f;
  #pragma unroll
  for (int k = 0; k < NCB; ++k) S += p[k].y * __expf(p[k].x - M);
  float v = M + logf(S) - diag[i];

  #pragma unroll
  for (int off = 1; off < 64; off <<= 1) v += __shfl_xor(v, off);
  __shared__ float wss[4];
  if ((threadIdx.x & 63) == 0) wss[threadIdx.x >> 6] = v;
  __syncthreads();
  if (threadIdx.x == 0)
    blocksum[blockIdx.x] = wss[0] + wss[1] + wss[2] + wss[3];
}

// ---------------- finalize 2: sum 16 block partials, divide ----------------
__global__ void finalize2_kernel(const float* __restrict__ blocksum, float* __restrict__ out)
{
  float s = 0.f;
  #pragma unroll
  for (int k = 0; k < 16; ++k) s += blocksum[k];
  out[0] = s * (1.0f / (float)NBATCH);
}

extern "C" void kernel_launch(void* const* d_in, const int* in_sizes, int n_in,
                              void* d_out, int out_size, void* d_ws, size_t ws_size,
                              hipStream_t stream) {
  const float* qm  = (const float*)d_in[0];
  const float* qls = (const float*)d_in[1];
  const float* tm  = (const float*)d_in[2];
  const float* tls = (const float*)d_in[3];
  const float* eq  = (const float*)d_in[4];
  const float* ek  = (const float*)d_in[5];
  float* out = (float*)d_out;

  char* ws = (char*)d_ws;
  unsigned short* Abf = (unsigned short*)ws;                          // 4 MB
  unsigned short* Bbf = (unsigned short*)(ws + (size_t)4194304);      // 4 MB
  float2* partial = (float2*)(ws + (size_t)8388608);                  // 512 KB (4096 x 16)
  float*  diag    = (float*)(ws + (size_t)8388608 + 524288);          // 16 KB
  float*  blocksum= (float*)(ws + (size_t)8388608 + 524288 + 16384);  // 64 B

  prep_kernel<<<dim3(NBATCH * 2 / 4), 256, 0, stream>>>(qm, qls, eq, tm, tls, ek, Abf, Bbf);
  gemm_lse_kernel<<<dim3(NCB, NCB), 512, 131072, stream>>>(Abf, Bbf, partial, diag);
  finalize1_kernel<<<NBATCH / 256, 256, 0, stream>>>(partial, diag, blocksum);
  finalize2_kernel<<<1, 1, 0, stream>>>(blocksum, out);
}